// Round 5
// baseline (1075.650 us; speedup 1.0000x reference)
//
#include <hip/hip_runtime.h>
#include <math.h>

// DeltaNetTemporal: B=16, N=4096, C=256, H=4, D=64.
// Interface dtypes: ALL fp32. Internal: fp16 MFMA GEMMs, fp32 state math.
// R5: state_pass ILP — 2 rows/iter, 4-way split accumulators, 8-row tiles.

typedef _Float16 f16;
typedef f16 f16x8 __attribute__((ext_vector_type(8)));
typedef float f32x4 __attribute__((ext_vector_type(4)));

// 8 fp32 -> 8 fp16
__device__ __forceinline__ f16x8 cvt8(const float* q) {
  float4 a = *(const float4*)q;
  float4 b = *(const float4*)(q + 4);
  f16x8 r;
  r[0] = (f16)a.x; r[1] = (f16)a.y; r[2] = (f16)a.z; r[3] = (f16)a.w;
  r[4] = (f16)b.x; r[5] = (f16)b.y; r[6] = (f16)b.z; r[7] = (f16)b.w;
  return r;
}

// ---------------- beta ----------------
__global__ __launch_bounds__(256) void beta_kernel(
    const float* __restrict__ x, const float* __restrict__ Wb,
    float* __restrict__ betaArr) {
  int t = threadIdx.x;
  int wave = t >> 6, lane = t & 63;
  size_t row = (size_t)blockIdx.x * 4 + wave;  // 0..65535 = b*4096+n
  float4 xv = *(const float4*)(x + row * 256 + lane * 4);
  float p[4];
#pragma unroll
  for (int h = 0; h < 4; ++h) {
    float4 wv = *(const float4*)(Wb + h * 256 + lane * 4);
    float s = xv.x * wv.x + xv.y * wv.y + xv.z * wv.z + xv.w * wv.w;
#pragma unroll
    for (int off = 32; off; off >>= 1) s += __shfl_xor(s, off);
    p[h] = s;
  }
  if (lane < 4) {
    float z = p[lane];
    size_t b = row >> 12, n = row & 4095;
    betaArr[((b * 4 + (size_t)lane) << 12) + n] = 1.f / (1.f + __expf(-z));
  }
}

// ---------------- fp16 MFMA GEMM: C[128-row tiles] = A @ W^T ----------------
template <typename AT, typename CT>
__global__ __launch_bounds__(256) void gemm_bt(
    const AT* __restrict__ A, int lda, int m_base,
    const float* __restrict__ B0, const float* __restrict__ B1,
    const float* __restrict__ B2, CT* __restrict__ C, int ldc) {
  __shared__ f16 As[128][72];  // +8 pad
  __shared__ f16 Bs[128][72];
  const int t = threadIdx.x;
  const int m0 = blockIdx.y * 128;
  const int n0 = blockIdx.x * 128;
  const float* Bsel = (n0 < 256) ? B0 : ((n0 < 512) ? B1 : B2);
  const int nin = n0 & 255;
  const int wave = t >> 6, lane = t & 63;
  const int wm = (wave >> 1) * 64, wn = (wave & 1) * 64;
  const int fr = lane & 15, fq = lane >> 4;
  f32x4 acc[4][4] = {};
#pragma unroll 1
  for (int kt = 0; kt < 4; ++kt) {
    const int k0 = kt * 64;
#pragma unroll
    for (int i = 0; i < 4; ++i) {
      int id = i * 256 + t;
      int row = id >> 3, cc = id & 7;
      if constexpr (__is_same(AT, float)) {
        *(f16x8*)&As[row][cc * 8] =
            cvt8(A + (size_t)(m_base + m0 + row) * lda + k0 + cc * 8);
      } else {
        *(uint4*)&As[row][cc * 8] =
            *(const uint4*)(A + (size_t)(m_base + m0 + row) * lda + k0 + cc * 8);
      }
      *(f16x8*)&Bs[row][cc * 8] =
          cvt8(Bsel + (size_t)(nin + row) * 256 + k0 + cc * 8);
    }
    __syncthreads();
#pragma unroll
    for (int ks = 0; ks < 2; ++ks) {
      f16x8 afr[4], bfr[4];
#pragma unroll
      for (int mi = 0; mi < 4; ++mi)
        afr[mi] = *(const f16x8*)&As[wm + mi * 16 + fr][ks * 32 + fq * 8];
#pragma unroll
      for (int ni = 0; ni < 4; ++ni)
        bfr[ni] = *(const f16x8*)&Bs[wn + ni * 16 + fr][ks * 32 + fq * 8];
#pragma unroll
      for (int mi = 0; mi < 4; ++mi)
#pragma unroll
        for (int ni = 0; ni < 4; ++ni)
          acc[mi][ni] = __builtin_amdgcn_mfma_f32_16x16x32_f16(
              afr[mi], bfr[ni], acc[mi][ni], 0, 0, 0);
    }
    __syncthreads();
  }
#pragma unroll
  for (int mi = 0; mi < 4; ++mi)
#pragma unroll
    for (int ni = 0; ni < 4; ++ni)
#pragma unroll
      for (int rr = 0; rr < 4; ++rr) {
        int row = m0 + wm + mi * 16 + fq * 4 + rr;  // C/D: row=(lane>>4)*4+reg
        int col = n0 + wn + ni * 16 + fr;           //      col=lane&15
        C[(size_t)row * ldc + col] = (CT)acc[mi][ni][rr];
      }
}

// ---------------- state pass (per chunk of 4 batches) ----------------
// block = 256 thr = (h = t>>6) x (i = t&63); one block per (b, 8-row tile).
// 2 rows per iteration, 4-way split accumulators, wave-local q/k exchange,
// deferred RMSNorm (1 block-wide barrier).
__global__ __launch_bounds__(256) void state_pass(
    f16* __restrict__ qkv, const float* __restrict__ S, int b_base,
    const float* __restrict__ betaArr, const float* __restrict__ g_rms,
    float* __restrict__ err_sum, float* __restrict__ key_sum) {
  const int t = threadIdx.x;
  const int h = t >> 6, lane = t & 63;
  const int b = b_base + blockIdx.y;  // global batch
  const int tile = blockIdx.x;        // 8-row tile
  float sd[64];  // 0.95 * S[b][h][lane][:] in registers
  {
    const float* Srow = S + (((size_t)b * 4 + h) * 64 + lane) * 64;
#pragma unroll
    for (int j4 = 0; j4 < 16; ++j4) {
      float4 v = *(const float4*)(Srow + j4 * 4);
      sd[j4 * 4 + 0] = 0.95f * v.x;
      sd[j4 * 4 + 1] = 0.95f * v.y;
      sd[j4 * 4 + 2] = 0.95f * v.z;
      sd[j4 * 4 + 3] = 0.95f * v.w;
    }
  }
  float g = g_rms[t];
  __shared__ float qs[2][256], ks[2][256];
  __shared__ float red[4][8];   // [head][row] sumsq
  __shared__ f16 ybuf[8][256];  // un-normalized y tile
  const float* betaBH = betaArr + (((size_t)b * 4 + h) << 12) + (size_t)tile * 8;
  const size_t row0 = (size_t)blockIdx.y * 4096 + (size_t)tile * 8;
  float errA = 0.f, keyA = 0.f;
#pragma unroll
  for (int rp = 0; rp < 4; ++rp) {
    const int ra = rp * 2, rb = ra + 1;
    const f16* pa = qkv + (row0 + ra) * 768;
    const f16* pb = pa + 768;
    // all 6 loads issued together (independent)
    float qva = (float)pa[t], kra = (float)pa[256 + t], vva = (float)pa[512 + t];
    float qvb = (float)pb[t], krb = (float)pb[256 + t], vvb = (float)pb[512 + t];
    float bta = betaBH[ra], btb = betaBH[rb];
    float kea = kra > 0.f ? kra + 1.f : __expf(kra);  // elu+1
    float keb = krb > 0.f ? krb + 1.f : __expf(krb);
    float sa = kea * kea, sb = keb * keb;
#pragma unroll
    for (int off = 32; off; off >>= 1) {  // two independent chains
      sa += __shfl_xor(sa, off);
      sb += __shfl_xor(sb, off);
    }
    float kta = kea / (sqrtf(sa) + 1e-6f);
    float ktb = keb / (sqrtf(sb) + 1e-6f);
    keyA += kta + ktb;
    qs[0][t] = qva; ks[0][t] = kta;
    qs[1][t] = qvb; ks[1][t] = ktb;
    __builtin_amdgcn_wave_barrier();  // same-wave LDS ordering only
    const float* qa_ = &qs[0][h * 64];
    const float* ka_ = &ks[0][h * 64];
    const float* qb_ = &qs[1][h * 64];
    const float* kb_ = &ks[1][h * 64];
    float yA[4] = {0, 0, 0, 0}, pA[4] = {0, 0, 0, 0};
    float yB[4] = {0, 0, 0, 0}, pB[4] = {0, 0, 0, 0};
#pragma unroll
    for (int j4 = 0; j4 < 16; ++j4) {
      float4 qa4 = *(const float4*)(qa_ + j4 * 4);
      float4 ka4 = *(const float4*)(ka_ + j4 * 4);
      float4 qb4 = *(const float4*)(qb_ + j4 * 4);
      float4 kb4 = *(const float4*)(kb_ + j4 * 4);
      const int a = j4 & 3;  // 16 independent FMA chains
      float s0 = sd[j4*4], s1 = sd[j4*4+1], s2v = sd[j4*4+2], s3 = sd[j4*4+3];
      yA[a] += s0*qa4.x + s1*qa4.y + s2v*qa4.z + s3*qa4.w;
      pA[a] += s0*ka4.x + s1*ka4.y + s2v*ka4.z + s3*ka4.w;
      yB[a] += s0*qb4.x + s1*qb4.y + s2v*qb4.z + s3*qb4.w;
      pB[a] += s0*kb4.x + s1*kb4.y + s2v*kb4.z + s3*kb4.w;
    }
    __builtin_amdgcn_wave_barrier();  // keep qs/ks live until reads done
    float ya = (yA[0] + yA[1]) + (yA[2] + yA[3]);
    float pra = (pA[0] + pA[1]) + (pA[2] + pA[3]);
    float yb = (yB[0] + yB[1]) + (yB[2] + yB[3]);
    float prb = (pB[0] + pB[1]) + (pB[2] + pB[3]);
    errA += bta * (vva - pra) + btb * (vvb - prb);
    float wa = ya * ya, wb = yb * yb;
#pragma unroll
    for (int off = 32; off; off >>= 1) {
      wa += __shfl_xor(wa, off);
      wb += __shfl_xor(wb, off);
    }
    if (lane == 0) { red[h][ra] = wa; red[h][rb] = wb; }
    ybuf[ra][t] = (f16)ya;
    ybuf[rb][t] = (f16)yb;
  }
  __syncthreads();  // the only block-wide barrier
#pragma unroll
  for (int r = 0; r < 8; ++r) {
    float tot = red[0][r] + red[1][r] + red[2][r] + red[3][r];
    float scale = rsqrtf(tot * (1.f / 256.f) + 1e-6f);
    qkv[(row0 + r) * 768 + t] = (f16)((float)ybuf[r][t] * scale * g);
  }
  atomicAdd(&err_sum[(size_t)b * 256 + t], errA);
  atomicAdd(&key_sum[(size_t)b * 256 + t], keyA);
}

// ---------------- S_new finalize ----------------
__global__ __launch_bounds__(256) void finalize_S(
    const float* __restrict__ S, const float* __restrict__ err_sum,
    const float* __restrict__ key_sum, float* __restrict__ Sout) {
  int bh = blockIdx.x;  // b*4+h
  int b = bh >> 2;
  const float* eb = err_sum + (size_t)b * 256 + (size_t)(bh & 3) * 64;
  const float* kb = key_sum + (size_t)b * 256 + (size_t)(bh & 3) * 64;
  for (int idx = threadIdx.x; idx < 4096; idx += 256) {
    int i = idx >> 6, j = idx & 63;
    float sdv = 0.95f * S[(size_t)bh * 4096 + idx];
    float v = sdv + (eb[i] * (1.f / 4096.f)) * (kb[j] * (1.f / 4096.f));
    v = fminf(10.f, fmaxf(-10.f, v));
    Sout[(size_t)bh * 4096 + idx] = v;
  }
}

extern "C" void kernel_launch(void* const* d_in, const int* in_sizes, int n_in,
                              void* d_out, int out_size, void* d_ws, size_t ws_size,
                              hipStream_t stream) {
  const float* x  = (const float*)d_in[0];
  const float* S  = (const float*)d_in[1];
  const float* Wq = (const float*)d_in[2];
  const float* Wk = (const float*)d_in[3];
  const float* Wv = (const float*)d_in[4];
  const float* Wb = (const float*)d_in[5];
  const float* Wo = (const float*)d_in[6];
  const float* g  = (const float*)d_in[7];

  char* w = (char*)d_ws;
  f16*   qkvc    = (f16*)w;                     // 16384*768*2 = 25,165,824
  float* betaArr = (float*)(w + 25165824);      // 16*4*4096*4 =  1,048,576
  float* sums    = (float*)(w + 26214400);      // 2*4096*4    =     32,768
  float* err_sum = sums;
  float* key_sum = sums + 4096;

  float* out  = (float*)d_out;                  // [16,4096,256] fp32
  float* Sout = out + (size_t)16 * 4096 * 256;  // [16,4,64,64]  fp32

  hipMemsetAsync(sums, 0, 32768, stream);
  beta_kernel<<<16384, 256, 0, stream>>>(x, Wb, betaArr);
  for (int c = 0; c < 4; ++c) {
    int m_base = c * 16384;  // row chunk = 4 batches
    gemm_bt<float, f16><<<dim3(6, 128), 256, 0, stream>>>(
        x, 256, m_base, Wq, Wk, Wv, qkvc, 768);
    state_pass<<<dim3(512, 4), 256, 0, stream>>>(qkvc, S, c * 4, betaArr, g,
                                                 err_sum, key_sum);
    gemm_bt<f16, float><<<dim3(2, 128), 256, 0, stream>>>(
        qkvc, 768, 0, Wo, Wo, Wo, out + (size_t)m_base * 256, 256);
  }
  finalize_S<<<64, 256, 0, stream>>>(S, err_sum, key_sum, Sout);
}

// Round 6
// 329.250 us; speedup vs baseline: 3.2670x; 3.2670x over previous
//
#include <hip/hip_runtime.h>
#include <math.h>

// DeltaNetTemporal: B=16, N=4096, C=256, H=4, D=64.  All I/O fp32.
// R6: state_pass eliminated by linearity:
//   y    = x @ (0.95*S[b,h] @ Wq_h)^T           (fold + GEMM)
//   pred-sums: kbsum = sum(beta*k'), err = (Wv@xbsum - Sd@kbsum)/4096
//   v-GEMM eliminated: sum(beta*v) = Wv @ sum(beta*x)
// Pipeline: memset -> beta+xbsum -> kGEMM(+elu/L2norm/col-sum epilogue)
//           -> fold M -> 2x[ yGEMM(+rowssq) -> outGEMM(RMSNorm-on-stage) ] -> finalize.
// Workspace 19.3 MB.

typedef _Float16 f16;
typedef f16 f16x8 __attribute__((ext_vector_type(8)));
typedef float f32x4 __attribute__((ext_vector_type(4)));

__device__ __forceinline__ f16x8 cvt8(const float* q) {
  float4 a = *(const float4*)q;
  float4 b = *(const float4*)(q + 4);
  f16x8 r;
  r[0] = (f16)a.x; r[1] = (f16)a.y; r[2] = (f16)a.z; r[3] = (f16)a.w;
  r[4] = (f16)b.x; r[5] = (f16)b.y; r[6] = (f16)b.z; r[7] = (f16)b.w;
  return r;
}

// ---------------- beta + xbsum ----------------
// grid 256: b = blk>>4, tile = blk&15 (256 rows). beta = sigmoid(x.Wb[h]);
// xbsum[b,h,:] += beta * x  (register accum -> LDS -> global atomics).
__global__ __launch_bounds__(256) void beta_xbsum(
    const float* __restrict__ x, const float* __restrict__ Wb,
    float* __restrict__ betaArr, float* __restrict__ xbsum) {
  const int t = threadIdx.x;
  const int wave = t >> 6, lane = t & 63;
  const int b = blockIdx.x >> 4;
  const int tile = blockIdx.x & 15;
  float4 wb[4];
#pragma unroll
  for (int h = 0; h < 4; ++h) wb[h] = *(const float4*)(Wb + h * 256 + lane * 4);
  float xacc[4][4] = {};  // [h][j], c = lane*4+j
  const size_t rowbase = (size_t)b * 4096 + tile * 256;
#pragma unroll 1
  for (int i = 0; i < 64; ++i) {
    int r = i * 4 + wave;
    float4 xv = *(const float4*)(x + (rowbase + r) * 256 + lane * 4);
    float p0, p1, p2, p3;
#pragma unroll
    for (int h = 0; h < 4; ++h) {
      float s = xv.x * wb[h].x + xv.y * wb[h].y + xv.z * wb[h].z + xv.w * wb[h].w;
#pragma unroll
      for (int off = 32; off; off >>= 1) s += __shfl_xor(s, off);
      float bh = 1.f / (1.f + __expf(-s));
      if (h == 0) p0 = bh; else if (h == 1) p1 = bh; else if (h == 2) p2 = bh; else p3 = bh;
      xacc[h][0] += bh * xv.x; xacc[h][1] += bh * xv.y;
      xacc[h][2] += bh * xv.z; xacc[h][3] += bh * xv.w;
    }
    if (lane < 4) {
      float z = (lane == 0) ? p0 : (lane == 1) ? p1 : (lane == 2) ? p2 : p3;
      betaArr[((size_t)(b * 4 + lane) << 12) + tile * 256 + r] = z;
    }
  }
  __shared__ float xbp[4][4][256];  // [wave][h][c]
#pragma unroll
  for (int h = 0; h < 4; ++h)
#pragma unroll
    for (int j = 0; j < 4; ++j) xbp[wave][h][lane * 4 + j] = xacc[h][j];
  __syncthreads();
  for (int idx = t; idx < 1024; idx += 256) {
    int h = idx >> 8, c = idx & 255;
    float s = xbp[0][h][c] + xbp[1][h][c] + xbp[2][h][c] + xbp[3][h][c];
    atomicAdd(&xbsum[(b * 4 + h) * 256 + c], s);
  }
}

// ---------------- k-GEMM with elu/L2norm/col-sum epilogue ----------------
// k = x @ Wk^T, k' = elu(k)+1 normalized per (token,head); accumulates
// ksum[bh][d] += k', kbsum[bh][d] += beta*k'. k never written to HBM.
__global__ __launch_bounds__(256) void kgemm_sums(
    const float* __restrict__ x, const float* __restrict__ Wk,
    const float* __restrict__ betaArr,
    float* __restrict__ ksum, float* __restrict__ kbsum) {
  __shared__ union {
    struct { f16 A[128][72]; f16 B[128][72]; } s;
    f16 K[128][132];
  } u;
  __shared__ float bstage[2][128];
  const int t = threadIdx.x;
  const int m0 = blockIdx.y * 128;
  const int n0 = blockIdx.x * 128;  // heads n0>>6 .. +1
  const int b = m0 >> 12;
  const int wave = t >> 6, lane = t & 63;
  const int wm = (wave >> 1) * 64, wn = (wave & 1) * 64;
  const int fr = lane & 15, fq = lane >> 4;
  {
    int hh = t >> 7, r = t & 127;
    bstage[hh][r] =
        betaArr[((size_t)(b * 4 + (n0 >> 6) + hh) << 12) + (m0 & 4095) + r];
  }
  f32x4 acc[4][4] = {};
#pragma unroll 1
  for (int kt = 0; kt < 4; ++kt) {
    const int k0 = kt * 64;
#pragma unroll
    for (int i = 0; i < 4; ++i) {
      int id = i * 256 + t;
      int row = id >> 3, cc = id & 7;
      *(f16x8*)&u.s.A[row][cc * 8] =
          cvt8(x + (size_t)(m0 + row) * 256 + k0 + cc * 8);
      *(f16x8*)&u.s.B[row][cc * 8] =
          cvt8(Wk + (size_t)(n0 + row) * 256 + k0 + cc * 8);
    }
    __syncthreads();
#pragma unroll
    for (int ks = 0; ks < 2; ++ks) {
      f16x8 afr[4], bfr[4];
#pragma unroll
      for (int mi = 0; mi < 4; ++mi)
        afr[mi] = *(const f16x8*)&u.s.A[wm + mi * 16 + fr][ks * 32 + fq * 8];
#pragma unroll
      for (int ni = 0; ni < 4; ++ni)
        bfr[ni] = *(const f16x8*)&u.s.B[wn + ni * 16 + fr][ks * 32 + fq * 8];
#pragma unroll
      for (int mi = 0; mi < 4; ++mi)
#pragma unroll
        for (int ni = 0; ni < 4; ++ni)
          acc[mi][ni] = __builtin_amdgcn_mfma_f32_16x16x32_f16(
              afr[mi], bfr[ni], acc[mi][ni], 0, 0, 0);
    }
    __syncthreads();
  }
  // elu+1, L2-normalize per (row, head) — head == this wave's 64-col range.
#pragma unroll
  for (int mi = 0; mi < 4; ++mi)
#pragma unroll
    for (int rr = 0; rr < 4; ++rr) {
      float s = 0.f;
#pragma unroll
      for (int ni = 0; ni < 4; ++ni) {
        float v = acc[mi][ni][rr];
        v = v > 0.f ? v + 1.f : __expf(v);
        acc[mi][ni][rr] = v;
        s += v * v;
      }
#pragma unroll
      for (int off = 1; off < 16; off <<= 1) s += __shfl_xor(s, off);
      float inv = 1.f / (sqrtf(s) + 1e-6f);
#pragma unroll
      for (int ni = 0; ni < 4; ++ni) acc[mi][ni][rr] *= inv;
    }
  // k' -> LDS (aliases A/B staging; all waves past final barrier)
#pragma unroll
  for (int mi = 0; mi < 4; ++mi)
#pragma unroll
    for (int ni = 0; ni < 4; ++ni)
#pragma unroll
      for (int rr = 0; rr < 4; ++rr)
        u.K[wm + mi * 16 + fq * 4 + rr][wn + ni * 16 + fr] = (f16)acc[mi][ni][rr];
  __syncthreads();
  if (t < 128) {
    const int c = t, hl = c >> 6;
    float sk = 0.f, skb = 0.f;
#pragma unroll 4
    for (int r = 0; r < 128; ++r) {
      float v = (float)u.K[r][c];
      float be = bstage[hl][r];
      sk += v;
      skb += be * v;
    }
    int gh = b * 4 + (n0 >> 6) + hl;
    atomicAdd(&ksum[gh * 64 + (c & 63)], sk);
    atomicAdd(&kbsum[gh * 64 + (c & 63)], skb);
  }
}

// ---------------- fold: M[b][(h,d)][c] = 0.95 * S[b,h] @ Wq_h ----------------
__global__ __launch_bounds__(256) void fold_M(
    const float* __restrict__ S, const float* __restrict__ Wq,
    f16* __restrict__ M) {
  const int bh = blockIdx.x;
  const int h = bh & 3;
  const int t = threadIdx.x;  // column c
  __shared__ float Sl[64][64];
  for (int i = t; i < 4096; i += 256)
    ((float*)Sl)[i] = 0.95f * S[(size_t)bh * 4096 + i];
  __syncthreads();
  float m[64] = {};
#pragma unroll 1
  for (int e = 0; e < 64; ++e) {
    float wv = Wq[(size_t)(h * 64 + e) * 256 + t];
#pragma unroll
    for (int d = 0; d < 64; ++d) m[d] += Sl[d][e] * wv;
  }
  f16* Mb = M + (size_t)(bh >> 2) * 65536;
#pragma unroll
  for (int d = 0; d < 64; ++d)
    Mb[(size_t)(h * 64 + d) * 256 + t] = (f16)m[d];
}

// ---------------- y-GEMM: y = x @ M[b]^T, + per-row sumsq atomics ----------------
__global__ __launch_bounds__(256) void ygemm_ssq(
    const float* __restrict__ x, int m_base, const f16* __restrict__ M,
    f16* __restrict__ y, float* __restrict__ rowssq) {
  __shared__ f16 As[128][72];
  __shared__ f16 Bs[128][72];
  const int t = threadIdx.x;
  const int m0 = blockIdx.y * 128;  // local row within half
  const int n0 = blockIdx.x * 128;
  const int b = (m_base + m0) >> 12;
  const f16* Mb = M + (size_t)b * 65536;
  const int wave = t >> 6, lane = t & 63;
  const int wm = (wave >> 1) * 64, wn = (wave & 1) * 64;
  const int fr = lane & 15, fq = lane >> 4;
  f32x4 acc[4][4] = {};
#pragma unroll 1
  for (int kt = 0; kt < 4; ++kt) {
    const int k0 = kt * 64;
#pragma unroll
    for (int i = 0; i < 4; ++i) {
      int id = i * 256 + t;
      int row = id >> 3, cc = id & 7;
      *(f16x8*)&As[row][cc * 8] =
          cvt8(x + (size_t)(m_base + m0 + row) * 256 + k0 + cc * 8);
      *(uint4*)&Bs[row][cc * 8] =
          *(const uint4*)(Mb + (size_t)(n0 + row) * 256 + k0 + cc * 8);
    }
    __syncthreads();
#pragma unroll
    for (int ks = 0; ks < 2; ++ks) {
      f16x8 afr[4], bfr[4];
#pragma unroll
      for (int mi = 0; mi < 4; ++mi)
        afr[mi] = *(const f16x8*)&As[wm + mi * 16 + fr][ks * 32 + fq * 8];
#pragma unroll
      for (int ni = 0; ni < 4; ++ni)
        bfr[ni] = *(const f16x8*)&Bs[wn + ni * 16 + fr][ks * 32 + fq * 8];
#pragma unroll
      for (int mi = 0; mi < 4; ++mi)
#pragma unroll
        for (int ni = 0; ni < 4; ++ni)
          acc[mi][ni] = __builtin_amdgcn_mfma_f32_16x16x32_f16(
              afr[mi], bfr[ni], acc[mi][ni], 0, 0, 0);
    }
    __syncthreads();
  }
#pragma unroll
  for (int mi = 0; mi < 4; ++mi)
#pragma unroll
    for (int rr = 0; rr < 4; ++rr) {
      float s = 0.f;
#pragma unroll
      for (int ni = 0; ni < 4; ++ni) {
        float v = acc[mi][ni][rr];
        s += v * v;
        int row = m0 + wm + mi * 16 + fq * 4 + rr;
        int col = n0 + wn + ni * 16 + fr;
        y[(size_t)row * 256 + col] = (f16)v;
      }
#pragma unroll
      for (int off = 1; off < 16; off <<= 1) s += __shfl_xor(s, off);
      if (fr == 0)
        atomicAdd(&rowssq[m0 + wm + mi * 16 + fq * 4 + rr], s);
    }
}

// ---------------- out-GEMM: out = RMSNorm(y)*g @ Wo^T ----------------
__global__ __launch_bounds__(256) void ogemm_scaled(
    const f16* __restrict__ y, const float* __restrict__ rowssq,
    const float* __restrict__ g_rms, const float* __restrict__ Wo,
    float* __restrict__ out, int m_base) {
  __shared__ f16 As[128][72];
  __shared__ f16 Bs[128][72];
  const int t = threadIdx.x;
  const int m0 = blockIdx.y * 128;  // local row within half
  const int n0 = blockIdx.x * 128;
  const int wave = t >> 6, lane = t & 63;
  const int wm = (wave >> 1) * 64, wn = (wave & 1) * 64;
  const int fr = lane & 15, fq = lane >> 4;
  f32x4 acc[4][4] = {};
#pragma unroll 1
  for (int kt = 0; kt < 4; ++kt) {
    const int k0 = kt * 64;
#pragma unroll
    for (int i = 0; i < 4; ++i) {
      int id = i * 256 + t;
      int row = id >> 3, cc = id & 7;
      float rs = rsqrtf(rowssq[m0 + row] * (1.f / 256.f) + 1e-6f);
      const f16* yp = y + (size_t)(m0 + row) * 256 + k0 + cc * 8;
      const float* gp = g_rms + k0 + cc * 8;
      f16x8 a;
#pragma unroll
      for (int j = 0; j < 8; ++j) a[j] = (f16)((float)yp[j] * rs * gp[j]);
      *(f16x8*)&As[row][cc * 8] = a;
      *(f16x8*)&Bs[row][cc * 8] =
          cvt8(Wo + (size_t)(n0 + row) * 256 + k0 + cc * 8);
    }
    __syncthreads();
#pragma unroll
    for (int ks = 0; ks < 2; ++ks) {
      f16x8 afr[4], bfr[4];
#pragma unroll
      for (int mi = 0; mi < 4; ++mi)
        afr[mi] = *(const f16x8*)&As[wm + mi * 16 + fr][ks * 32 + fq * 8];
#pragma unroll
      for (int ni = 0; ni < 4; ++ni)
        bfr[ni] = *(const f16x8*)&Bs[wn + ni * 16 + fr][ks * 32 + fq * 8];
#pragma unroll
      for (int mi = 0; mi < 4; ++mi)
#pragma unroll
        for (int ni = 0; ni < 4; ++ni)
          acc[mi][ni] = __builtin_amdgcn_mfma_f32_16x16x32_f16(
              afr[mi], bfr[ni], acc[mi][ni], 0, 0, 0);
    }
    __syncthreads();
  }
#pragma unroll
  for (int mi = 0; mi < 4; ++mi)
#pragma unroll
    for (int ni = 0; ni < 4; ++ni)
#pragma unroll
      for (int rr = 0; rr < 4; ++rr) {
        int row = m_base + m0 + wm + mi * 16 + fq * 4 + rr;
        int col = n0 + wn + ni * 16 + fr;
        out[(size_t)row * 256 + col] = acc[mi][ni][rr];
      }
}

// ---------------- finalize S ----------------
// err = (Wv_h @ xbsum - 0.95*S @ kbsum)/4096 ; key = ksum/4096
// S_new = clip(0.95*S + outer(err, key), +-10)
__global__ __launch_bounds__(256) void finalize_S(
    const float* __restrict__ S, const float* __restrict__ Wv,
    const float* __restrict__ xbsum, const float* __restrict__ ksum,
    const float* __restrict__ kbsum, float* __restrict__ Sout) {
  const int bh = blockIdx.x;
  const int h = bh & 3;
  const int t = threadIdx.x;
  const int wave = t >> 6, lane = t & 63;
  __shared__ float xb[256], kb[64], key[64], errv[64];
  xb[t] = xbsum[bh * 256 + t];
  if (t < 64) {
    kb[t] = kbsum[bh * 64 + t];
    key[t] = ksum[bh * 64 + t] * (1.f / 4096.f);
  }
  __syncthreads();
#pragma unroll 1
  for (int ri = 0; ri < 16; ++ri) {
    int i = wave * 16 + ri;
    float4 wv4 = *(const float4*)(Wv + (size_t)(h * 64 + i) * 256 + lane * 4);
    float4 xb4 = *(const float4*)(&xb[lane * 4]);
    float s = wv4.x * xb4.x + wv4.y * xb4.y + wv4.z * xb4.z + wv4.w * xb4.w;
    s -= 0.95f * S[(size_t)bh * 4096 + i * 64 + lane] * kb[lane];
#pragma unroll
    for (int off = 32; off; off >>= 1) s += __shfl_xor(s, off);
    if (lane == 0) errv[i] = s * (1.f / 4096.f);
  }
  __syncthreads();
  for (int idx = t; idx < 4096; idx += 256) {
    int i = idx >> 6, j = idx & 63;
    float v = 0.95f * S[(size_t)bh * 4096 + idx] + errv[i] * key[j];
    Sout[(size_t)bh * 4096 + idx] = fminf(10.f, fmaxf(-10.f, v));
  }
}

extern "C" void kernel_launch(void* const* d_in, const int* in_sizes, int n_in,
                              void* d_out, int out_size, void* d_ws, size_t ws_size,
                              hipStream_t stream) {
  const float* x  = (const float*)d_in[0];
  const float* S  = (const float*)d_in[1];
  const float* Wq = (const float*)d_in[2];
  const float* Wk = (const float*)d_in[3];
  const float* Wv = (const float*)d_in[4];
  const float* Wb = (const float*)d_in[5];
  const float* Wo = (const float*)d_in[6];
  const float* g  = (const float*)d_in[7];

  char* w = (char*)d_ws;
  float* betaArr = (float*)w;                    // 1,048,576 B
  f16*   M       = (f16*)(w + 1048576);          // 2,097,152 B
  f16*   y       = (f16*)(w + 3145728);          // 16,777,216 B (32768x256)
  float* rowssq  = (float*)(w + 19922944);       // 262,144 B (2 halves)
  float* xbsum   = (float*)(w + 20185088);       // 65,536 B
  float* ksum    = (float*)(w + 20250624);       // 16,384 B
  float* kbsum   = (float*)(w + 20267008);       // 16,384 B

  float* out  = (float*)d_out;                   // [16,4096,256] fp32
  float* Sout = out + (size_t)16 * 4096 * 256;   // [16,4,64,64]  fp32

  hipMemsetAsync(w + 19922944, 0, 360448, stream);  // rowssq..kbsum
  beta_xbsum<<<256, 256, 0, stream>>>(x, Wb, betaArr, xbsum);
  kgemm_sums<<<dim3(2, 512), 256, 0, stream>>>(x, Wk, betaArr, ksum, kbsum);
  fold_M<<<64, 256, 0, stream>>>(S, Wq, M);
  for (int half = 0; half < 2; ++half) {
    int m_base = half * 32768;
    ygemm_ssq<<<dim3(2, 256), 256, 0, stream>>>(x, m_base, M, y,
                                                rowssq + half * 32768);
    ogemm_scaled<<<dim3(2, 256), 256, 0, stream>>>(y, rowssq + half * 32768, g,
                                                   Wo, out, m_base);
  }
  finalize_S<<<64, 256, 0, stream>>>(S, Wv, xbsum, ksum, kbsum, Sout);
}